// Round 9
// baseline (682.735 us; speedup 1.0000x reference)
//
#include <hip/hip_runtime.h>
#include <hip/hip_bf16.h>

#define ALPHA 0.2f
// N=1024 particles, F_IN=6, NH=64, H=4 heads, T=12 steps.
// Identity: attend values are LINEAR in the 6-dim input row -> every head-attend
// runs in 6-dim space: out_h = (Sum_j w x_j) @ W_h; ELU(hv@W)@Wout is a per-row
// pointwise afterwards. Scores are linear too: s = x.(W@a_src), d = x.(W@a_dst).
// Dense per-row softmax; LDS is SoA-float2 (conflict-free); phase 2 is one
// persistent 128-block kernel with a no-reset generation barrier.

__device__ __forceinline__ float wredmax(float v){
  #pragma unroll
  for (int m = 1; m < 64; m <<= 1) v = fmaxf(v, __shfl_xor(v, m, 64));
  return v;
}

// ---------------- dtype detect + convert ----------------
__global__ void k_detect(const unsigned short* __restrict__ s, int n, int* __restrict__ flag){
  int i = blockIdx.x * 256 + threadIdx.x;
  if (i < n){
    unsigned short u = s[i];
    if ((u & 0x7F80u) == 0x7F80u) atomicOr(flag, 1);
  }
}

struct Ptr13 { const void* p[13]; };
__global__ void k_cvtAll(Ptr13 src, float* __restrict__ xs, float* __restrict__ wsW,
                         const int* __restrict__ flag){
  const int n = blockIdx.x * 256 + threadIdx.x;
  const int F = *flag;
  if (n < 73728){
    xs[n] = F ? ((const float*)src.p[0])[n]
              : __bfloat162float(((const __hip_bfloat16*)src.p[0])[n]);
    return;
  }
  const int m = n - 73728;
  if (m >= 10788) return;
  const int segend[12] = {1536,2048,3584,3596,5132,5644,7180,7192,8728,9240,10776,10788};
  const int dstoff[12] = {0,1536,2048,3584,3600,5136,5648,7184,7200,8736,9248,10784};
  int seg = 0;
  #pragma unroll
  for (int i = 0; i < 12; ++i) if (m >= segend[i]) seg = i + 1;
  const int local = m - (seg ? segend[seg - 1] : 0);
  float v;
  if (F) v = ((const float*)src.p[seg + 1])[local];
  else   v = __bfloat162float(((const __hip_bfloat16*)src.p[seg + 1])[local]);
  wsW[dstoff[seg] + local] = v;
}

// Wa[L][h][sd][8] = W @ a halves; zero h_cur (6144) + bar region (2048 ints).
__global__ void k_prew(const float* __restrict__ wsW, float* __restrict__ WaG,
                       float* __restrict__ h_cur, int* __restrict__ bar)
{
  const int gid = blockIdx.x * 256 + threadIdx.x;
  if (gid < 6144) h_cur[gid] = 0.f;
  else if (gid < 8192) bar[gid - 6144] = 0;
  if (blockIdx.x == 0 && threadIdx.x < 144){
    const int d = threadIdx.x;
    const int L = d / 48, r2 = d % 48, h = r2 / 12, sd = (r2 % 12) / 6, f = r2 % 6;
    const int Woff[3] = {0, 3600, 7200};     // Wx, Wh, Wy
    const int aoff[3] = {1536, 5136, 8736};  // ax, ah, ay
    float s = 0.f;
    for (int k = 0; k < 64; ++k)
      s += wsW[Woff[L] + h * 384 + f * 64 + k] * wsW[aoff[L] + h * 128 + sd * 64 + k];
    WaG[((L * 4 + h) * 2 + sd) * 8 + f] = s;
  }
}

// ---------------- dense 6-dim attend machinery (SoA float2 LDS) ----------------
__device__ __forceinline__ void stage_plain(const float* __restrict__ src,
    float2* __restrict__ f01, float2* __restrict__ f23, float2* __restrict__ f45,
    const int t){
  for (int i = t; i < 1024; i += 256){
    const float2* r = (const float2*)(src + i * 6);    // 8B-aligned
    f01[i] = r[0]; f23[i] = r[1]; f45[i] = r[2];
  }
}
__device__ __forceinline__ void stage_sum4(const float* __restrict__ src, // [4][1024][6]
    float2* __restrict__ f01, float2* __restrict__ f23, float2* __restrict__ f45,
    const int t){
  for (int i = t; i < 1024; i += 256){
    const float2* p0 = (const float2*)(src + i * 6);
    const float2* p1 = (const float2*)(src + 6144 + i * 6);
    const float2* p2 = (const float2*)(src + 12288 + i * 6);
    const float2* p3 = (const float2*)(src + 18432 + i * 6);
    float2 a, b, c;
    a.x = p0[0].x+p1[0].x+p2[0].x+p3[0].x; a.y = p0[0].y+p1[0].y+p2[0].y+p3[0].y;
    b.x = p0[1].x+p1[1].x+p2[1].x+p3[1].x; b.y = p0[1].y+p1[1].y+p2[1].y+p3[1].y;
    c.x = p0[2].x+p1[2].x+p2[2].x+p3[2].x; c.y = p0[2].y+p1[2].y+p2[2].y+p3[2].y;
    f01[i] = a; f23[i] = b; f45[i] = c;
  }
}
// fills dF, sS for rows [r0, r0+R); returns block-max d. (includes one barrier)
__device__ __forceinline__ float stage_scores(
    const float2* __restrict__ f01, const float2* __restrict__ f23,
    const float2* __restrict__ f45, float* __restrict__ dF,
    const float (&was)[6], const float (&wad)[6],
    float* __restrict__ sS, const int r0, const int R,
    float* __restrict__ red, const int t){
  float lmax = -1.0e30f;
  for (int r = t; r < 1024; r += 256){
    const float2 a = f01[r], b = f23[r], c = f45[r];
    const float d = a.x*wad[0] + a.y*wad[1] + b.x*wad[2] + b.y*wad[3]
                  + c.x*wad[4] + c.y*wad[5];
    dF[r] = d;
    lmax = fmaxf(lmax, d);
    if ((unsigned)(r - r0) < (unsigned)R)
      sS[r - r0] = a.x*was[0] + a.y*was[1] + b.x*was[2] + b.y*was[3]
                 + c.x*was[4] + c.y*was[5];
  }
  lmax = wredmax(lmax);
  if ((t & 63) == 0) red[t >> 6] = lmax;
  __syncthreads();
  return fmaxf(fmaxf(red[0], red[1]), fmaxf(red[2], red[3]));
}
// dense attend for NR rows/thread, lanes split j JG ways; after call all JG
// lanes hold the full sums (xor butterfly). acc[r][6] = den.
template<int NR, int JG>
__device__ __forceinline__ void attend_rows(
    const float2* __restrict__ f01, const float2* __restrict__ f23,
    const float2* __restrict__ f45, const float* __restrict__ dF,
    const float* s, const float dmax, const int jg, float acc[NR][7])
{
  float m[NR];
  #pragma unroll
  for (int r = 0; r < NR; ++r){
    float mm = s[r] + dmax; m[r] = fmaxf(mm, ALPHA * mm);
    #pragma unroll
    for (int c = 0; c < 7; ++c) acc[r][c] = 0.f;
  }
  for (int j = jg; j < 1024; j += JG){
    const float d = dF[j];
    const float2 a = f01[j], b = f23[j], c2 = f45[j];
    #pragma unroll
    for (int r = 0; r < NR; ++r){
      float e = s[r] + d; e = fmaxf(e, ALPHA * e);
      const float w = __expf(fminf(e - m[r], 0.f));
      acc[r][0] += w * a.x;  acc[r][1] += w * a.y;
      acc[r][2] += w * b.x;  acc[r][3] += w * b.y;
      acc[r][4] += w * c2.x; acc[r][5] += w * c2.y;
      acc[r][6] += w;
    }
  }
  #pragma unroll
  for (int mk = 1; mk < JG; mk <<= 1)
    #pragma unroll
    for (int r = 0; r < NR; ++r)
      #pragma unroll
      for (int c = 0; c < 7; ++c) acc[r][c] += __shfl_xor(acc[r][c], mk, 64);
}

#define FEAT_SHARED \
  __shared__ __align__(16) float2 f01_[1024]; \
  __shared__ __align__(16) float2 f23_[1024]; \
  __shared__ __align__(16) float2 f45_[1024]; \
  __shared__ float dF_[1024]; \
  __shared__ float red_[4];

// ---------------- phases 1/3: head attends ----------------
// grid (4 heads, 12 t, 16 rowgroups of 64), 256 thr: 4 lanes/row.
__launch_bounds__(256)
__global__ void k_dA(const float* __restrict__ X, const float* __restrict__ WaL,
                     const float* __restrict__ W64, const float* __restrict__ Wout,
                     float* __restrict__ y6part)
{
  FEAT_SHARED
  __shared__ float WS_[384], WoT_[384];
  __shared__ float sS[64];
  const int h = blockIdx.x, tb = blockIdx.y, r0 = blockIdx.z * 64;
  const int t = threadIdx.x;
  if (t < 384){
    WS_[t] = W64[h * 384 + t];
    const int f = t >> 6, k = t & 63;
    WoT_[f * 64 + k] = Wout[(h * 64 + k) * 6 + f];
  }
  float was[6], wad[6];
  #pragma unroll
  for (int c = 0; c < 6; ++c){ was[c] = WaL[h * 16 + c]; wad[c] = WaL[h * 16 + 8 + c]; }
  stage_plain(X + (size_t)tb * 6144, f01_, f23_, f45_, t);
  __syncthreads();
  const float dmax = stage_scores(f01_, f23_, f45_, dF_, was, wad, sS, r0, 64, red_, t);
  const int r = t >> 2, jg = t & 3;
  float sv[1] = { sS[r] };
  float acc[1][7];
  attend_rows<1, 4>(f01_, f23_, f45_, dF_, sv, dmax, jg, acc);
  const float inv = 1.f / acc[0][6];
  float hvv[6];
  #pragma unroll
  for (int c = 0; c < 6; ++c) hvv[c] = acc[0][c] * inv;
  // pointwise: k = jg + 4*kk (wave-uniform LDS broadcasts)
  float yp[6] = {0.f,0.f,0.f,0.f,0.f,0.f};
  for (int kk = 0; kk < 16; ++kk){
    const int k = jg + kk * 4;
    float o = 0.f;
    #pragma unroll
    for (int c = 0; c < 6; ++c) o += hvv[c] * WS_[c * 64 + k];
    o = o > 0.f ? o : (__expf(o) - 1.f);                 // ELU
    #pragma unroll
    for (int c = 0; c < 6; ++c) yp[c] += o * WoT_[c * 64 + k];
  }
  #pragma unroll
  for (int mk = 1; mk < 4; mk <<= 1)
    #pragma unroll
    for (int c = 0; c < 6; ++c) yp[c] += __shfl_xor(yp[c], mk, 64);
  if (jg == 0){
    float* dst = y6part + (((size_t)tb * 4 + h) * 1024 + r0 + r) * 6;
    #pragma unroll
    for (int c = 0; c < 6; ++c) dst[c] = yp[c];
  }
}

// phases 1/3: output attend. grid (16 rowgroups, 12 t), 256 thr, 4 lanes/row.
// MODE 0: f32out = hv (Lx). MODE 2: outv = addsrc + hv (final, dtype by flag).
template<int MODE>
__launch_bounds__(256)
__global__ void k_dB(const float* __restrict__ y6part, const float* __restrict__ ao,
                     const float* __restrict__ addsrc, float* __restrict__ f32out,
                     void* __restrict__ outv, const int* __restrict__ flag)
{
  FEAT_SHARED
  __shared__ float sS[64];
  const int r0 = blockIdx.x * 64, tb = blockIdx.y;
  const int t = threadIdx.x;
  float was[6], wad[6];
  #pragma unroll
  for (int c = 0; c < 6; ++c){ was[c] = ao[c]; wad[c] = ao[6 + c]; }
  stage_sum4(y6part + (size_t)tb * 24576, f01_, f23_, f45_, t);
  __syncthreads();
  const float dmax = stage_scores(f01_, f23_, f45_, dF_, was, wad, sS, r0, 64, red_, t);
  const int r = t >> 2, jg = t & 3;
  float sv[1] = { sS[r] };
  float acc[1][7];
  attend_rows<1, 4>(f01_, f23_, f45_, dF_, sv, dmax, jg, acc);
  if (jg == 0){
    const float inv = 1.f / acc[0][6];
    const int row = r0 + r;
    if (MODE == 0){
      float* dst = f32out + (size_t)tb * 6144 + row * 6;
      #pragma unroll
      for (int c = 0; c < 6; ++c) dst[c] = acc[0][c] * inv;
    } else {
      const float* a = addsrc + (size_t)tb * 6144 + row * 6;
      const int base = tb * 6144 + row * 6;
      if (*flag){
        float* dst = (float*)outv;
        #pragma unroll
        for (int c = 0; c < 6; ++c) dst[base + c] = a[c] + acc[0][c] * inv;
      } else {
        __hip_bfloat16* dst = (__hip_bfloat16*)outv;
        #pragma unroll
        for (int c = 0; c < 6; ++c) dst[base + c] = __float2bfloat16(a[c] + acc[0][c] * inv);
      }
    }
  }
}

// ---------------- phase 2: persistent 128-block kernel ----------------
// No-reset generation barrier: 16 leaf counters (8 arrivals, monotone), 1 root
// (16 arrivals, monotone), 1 release generation word. Pollers use device-scope
// atomic LOADS (no RMW) -> no serialization on the release line; no reset chain.
__device__ __forceinline__ void gbar(int* __restrict__ bar, const int bid, const int gen){
  __syncthreads();
  if (threadIdx.x == 0){
    __threadfence();
    const int lf = bid & 15;
    const int v = __hip_atomic_fetch_add(bar + lf * 32, 1, __ATOMIC_ACQ_REL,
                                         __HIP_MEMORY_SCOPE_AGENT);
    if (v == gen * 8 - 1){
      const int rr = __hip_atomic_fetch_add(bar + 600, 1, __ATOMIC_ACQ_REL,
                                            __HIP_MEMORY_SCOPE_AGENT);
      if (rr == gen * 16 - 1)
        __hip_atomic_store(bar + 640, gen, __ATOMIC_RELEASE, __HIP_MEMORY_SCOPE_AGENT);
    }
    while (__hip_atomic_load(bar + 640, __ATOMIC_ACQUIRE, __HIP_MEMORY_SCOPE_AGENT) < gen)
      __builtin_amdgcn_s_sleep(2);
    __threadfence();
  }
  __syncthreads();
}

__launch_bounds__(256)
__global__ void k_p2(float* __restrict__ h_cur, const float* __restrict__ Lx,
                     float* __restrict__ h_all, const float* __restrict__ WaL,
                     const float* __restrict__ W64, const float* __restrict__ Wout,
                     const float* __restrict__ ao, float* __restrict__ y6p,
                     int* __restrict__ bar)
{
  FEAT_SHARED
  __shared__ float WS_[384], WoT_[384];
  __shared__ float sS[32];
  const int bid = blockIdx.x, t = threadIdx.x;
  const int h = bid & 3, r0a = (bid >> 2) * 32;   // role A: head h, 32 rows
  const int r0b = bid * 8;                        // role B: 8 rows
  if (t < 384){
    WS_[t] = W64[h * 384 + t];
    const int f = t >> 6, k = t & 63;
    WoT_[f * 64 + k] = Wout[(h * 64 + k) * 6 + f];
  }
  float was[6], wad[6], aos[6], aod[6];
  #pragma unroll
  for (int c = 0; c < 6; ++c){
    was[c] = WaL[h * 16 + c]; wad[c] = WaL[h * 16 + 8 + c];
    aos[c] = ao[c];           aod[c] = ao[6 + c];
  }
  __syncthreads();

  for (int step = 0; step < 12; ++step){
    // ---- A: head attend + pointwise, 2 rows/thread (JG=16) ----
    stage_plain(h_cur, f01_, f23_, f45_, t);
    __syncthreads();
    {
      const float dmax = stage_scores(f01_, f23_, f45_, dF_, was, wad, sS, r0a, 32, red_, t);
      const int rr = t >> 4, jg = t & 15;
      float sv[2] = { sS[rr], sS[16 + rr] };
      float acc[2][7];
      attend_rows<2, 16>(f01_, f23_, f45_, dF_, sv, dmax, jg, acc);
      float hvv[2][6];
      #pragma unroll
      for (int r = 0; r < 2; ++r){
        const float inv = 1.f / acc[r][6];
        #pragma unroll
        for (int c = 0; c < 6; ++c) hvv[r][c] = acc[r][c] * inv;
      }
      float yp[2][6];
      #pragma unroll
      for (int r = 0; r < 2; ++r)
        #pragma unroll
        for (int c = 0; c < 6; ++c) yp[r][c] = 0.f;
      for (int kk = 0; kk < 4; ++kk){
        const int k = jg + kk * 16;
        #pragma unroll
        for (int r = 0; r < 2; ++r){
          float o = 0.f;
          #pragma unroll
          for (int c = 0; c < 6; ++c) o += hvv[r][c] * WS_[c * 64 + k];
          o = o > 0.f ? o : (__expf(o) - 1.f);
          #pragma unroll
          for (int c = 0; c < 6; ++c) yp[r][c] += o * WoT_[c * 64 + k];
        }
      }
      #pragma unroll
      for (int mk = 1; mk < 16; mk <<= 1)
        #pragma unroll
        for (int r = 0; r < 2; ++r)
          #pragma unroll
          for (int c = 0; c < 6; ++c) yp[r][c] += __shfl_xor(yp[r][c], mk, 64);
      if (jg == 0){
        #pragma unroll
        for (int r = 0; r < 2; ++r){
          float* dst = y6p + ((size_t)h * 1024 + r0a + r * 16 + rr) * 6;
          #pragma unroll
          for (int c = 0; c < 6; ++c) dst[c] = yp[r][c];
        }
      }
    }
    gbar(bar, bid, 2 * step + 1);
    // ---- B: output attend for rows r0b..r0b+7; h update ----
    stage_sum4(y6p, f01_, f23_, f45_, t);
    __syncthreads();
    {
      const float dmax = stage_scores(f01_, f23_, f45_, dF_, aos, aod, sS, r0b, 8, red_, t);
      const int r = t >> 5, jg = t & 31;
      float sv[1] = { sS[r] };
      float acc[1][7];
      attend_rows<1, 32>(f01_, f23_, f45_, dF_, sv, dmax, jg, acc);
      if (jg == 0){
        const float inv = 1.f / acc[0][6];
        const int row = r0b + r;
        const float* lx = Lx + (size_t)step * 6144 + row * 6;
        float* hc = h_cur + row * 6;
        float* ha = h_all + (size_t)step * 6144 + row * 6;
        #pragma unroll
        for (int c = 0; c < 6; ++c){
          const float hvn = lx[c] + acc[0][c] * inv;
          hc[c] = hvn; ha[c] = hvn;
        }
      }
    }
    gbar(bar, bid, 2 * step + 2);
  }
}

extern "C" void kernel_launch(void* const* d_in, const int* in_sizes, int n_in,
                              void* d_out, int out_size, void* d_ws, size_t ws_size,
                              hipStream_t stream) {
  (void)in_sizes; (void)n_in; (void)out_size;

  const size_t avail = ws_size / 4;
  if (avail < 570000u) return;   // ~2.3 MB needed

  float* ws = (float*)d_ws;
  size_t off = 0;
  int*   flag   = (int*)(ws + off); off += 16;
  float* xs     = ws + off; off += 73728;
  float* wsW    = ws + off; off += 10800;
  float* Lx     = ws + off; off += 73728;
  float* WaG    = ws + off; off += 256;
  float* h_cur  = ws + off; off += 6144;
  float* h_all  = ws + off; off += 73728;    // [12][1024][6]; h after step t
  float* y6part = ws + off; off += 294912;   // [12][4][1024][6]
  float* y6p    = ws + off; off += 24576;    // [4][1024][6]
  int*   bar    = (int*)(ws + off); off += 2048;

  hipMemsetAsync(flag, 0, 4, stream);
  k_detect<<<288, 256, 0, stream>>>((const unsigned short*)d_in[0], 73728, flag);
  Ptr13 ptrs;
  for (int i = 0; i < 13; ++i) ptrs.p[i] = d_in[i];
  k_cvtAll<<<331, 256, 0, stream>>>(ptrs, xs, wsW, flag);
  k_prew<<<32, 256, 0, stream>>>(wsW, WaG, h_cur, bar);

  float *Wx = wsW, *Wxo = wsW + 2048, *axo = wsW + 3584;
  float *Wh = wsW + 3600, *Who = wsW + 5648, *aho = wsW + 7184;
  float *Wy = wsW + 7200, *Wyo = wsW + 9248, *ayo = wsW + 10784;

  // Phase 1: Lx[t] = pat_layer(x_t, Wx, ax, Wxo, axo)
  k_dA<<<dim3(4, 12, 16), 256, 0, stream>>>(xs, WaG, Wx, Wxo, y6part);
  k_dB<0><<<dim3(16, 12), 256, 0, stream>>>(y6part, axo, nullptr, Lx, nullptr, flag);

  // Phase 2: one persistent kernel, 128 blocks, 12 steps, generation barrier.
  k_p2<<<128, 256, 0, stream>>>(h_cur, Lx, h_all, WaG + 64, Wh, Who, aho, y6p, bar);

  // Phase 3: y_t = x_t + pat_layer(h_t, Wy, ay, Wyo, ayo)
  k_dA<<<dim3(4, 12, 16), 256, 0, stream>>>(h_all, WaG + 128, Wy, Wyo, y6part);
  k_dB<2><<<dim3(16, 12), 256, 0, stream>>>(y6part, ayo, xs, nullptr, d_out, flag);
}